// Round 2
// baseline (1202.577 us; speedup 1.0000x reference)
//
#include <hip/hip_runtime.h>
#include <math.h>

#define NEG_SLOPE 0.2f

__device__ __forceinline__ float lrelu(float x) { return x >= 0.f ? x : NEG_SLOPE * x; }

// ---------------- CSR build (by dst) ----------------

__global__ void hist_kernel(const int* __restrict__ dst, int E, int* __restrict__ cnt) {
    int i = blockIdx.x * blockDim.x + threadIdx.x;
    int stride = gridDim.x * blockDim.x;
    for (; i < E; i += stride) atomicAdd(&cnt[dst[i]], 1);
}

__global__ void alloc_kernel(const int* __restrict__ cnt, int N,
                             int* __restrict__ start, int* __restrict__ total) {
    int i = blockIdx.x * blockDim.x + threadIdx.x;
    int stride = gridDim.x * blockDim.x;
    for (; i < N; i += stride) start[i] = atomicAdd(total, cnt[i] + 1);  // +1 self loop
}

__global__ void scatter_kernel(const int* __restrict__ src, const int* __restrict__ dst,
                               int E, int N, const int* __restrict__ start,
                               int* __restrict__ fill, int* __restrict__ col) {
    int i = blockIdx.x * blockDim.x + threadIdx.x;
    int stride = gridDim.x * blockDim.x;
    int tot = E + N;
    for (; i < tot; i += stride) {
        int s, d;
        if (i < E) { s = src[i]; d = dst[i]; }
        else       { s = i - E; d = s; }       // self loop
        int p = start[d] + atomicAdd(&fill[d], 1);
        col[p] = s;
    }
}

// ---------------- GEMM (128x128 weight) + alpha epilogue ----------------
// One wave per row; W staged in LDS. lane l computes channels l and l+64.

template <int H>
__global__ __launch_bounds__(256) void gemm_alpha_kernel(
    const float* __restrict__ X, const float* __restrict__ W,
    const float* __restrict__ avs, const float* __restrict__ avd,
    float* __restrict__ Hm, float* __restrict__ As, float* __restrict__ Ad, int N) {
    __shared__ float Wl[128 * 128];
    const int t = threadIdx.x;
    for (int k = t; k < 128 * 128 / 4; k += 256)
        ((float4*)Wl)[k] = ((const float4*)W)[k];
    __syncthreads();

    const int lane = t & 63;
    const int wid = (blockIdx.x * 256 + t) >> 6;
    const int nw = (gridDim.x * 256) >> 6;
    const float a_s0 = avs[lane], a_s1 = avs[64 + lane];
    const float a_d0 = avd[lane], a_d1 = avd[64 + lane];

    for (int i = wid; i < N; i += nw) {
        float x0 = X[i * 128 + lane];
        float x1 = X[i * 128 + 64 + lane];
        float acc0 = 0.f, acc1 = 0.f;
#pragma unroll 16
        for (int k = 0; k < 64; ++k) {
            float xv = __shfl(x0, k);
            acc0 += xv * Wl[k * 128 + lane];
            acc1 += xv * Wl[k * 128 + 64 + lane];
        }
#pragma unroll 16
        for (int k = 0; k < 64; ++k) {
            float xv = __shfl(x1, k);
            acc0 += xv * Wl[(64 + k) * 128 + lane];
            acc1 += xv * Wl[(64 + k) * 128 + 64 + lane];
        }
        Hm[i * 128 + lane] = acc0;
        Hm[i * 128 + 64 + lane] = acc1;

        float ps0 = acc0 * a_s0, ps1 = acc1 * a_s1;
        float pd0 = acc0 * a_d0, pd1 = acc1 * a_d1;
        if (H == 4) {
            // reduce within each 32-lane half (channels 0..31|32..63 -> heads 0|1; 64..95|96..127 -> heads 2|3)
#pragma unroll
            for (int m = 16; m >= 1; m >>= 1) {
                ps0 += __shfl_xor(ps0, m);
                ps1 += __shfl_xor(ps1, m);
                pd0 += __shfl_xor(pd0, m);
                pd1 += __shfl_xor(pd1, m);
            }
            if ((lane & 31) == 0) {
                int g = lane >> 5;
                As[i * 4 + g] = ps0;
                As[i * 4 + 2 + g] = ps1;
                Ad[i * 4 + g] = pd0;
                Ad[i * 4 + 2 + g] = pd1;
            }
        } else {
            float ps = ps0 + ps1, pd = pd0 + pd1;
#pragma unroll
            for (int m = 32; m >= 1; m >>= 1) {
                ps += __shfl_xor(ps, m);
                pd += __shfl_xor(pd, m);
            }
            if (lane == 0) { As[i] = ps; Ad[i] = pd; }
        }
    }
}

// ---------------- Aggregation layer 1 (H=4, +bias, ELU) ----------------
// One wave per dst node. lane l owns channels l and l+64.

__global__ __launch_bounds__(256) void agg1_kernel(
    const float* __restrict__ Hm, const int* __restrict__ col,
    const int* __restrict__ start, const int* __restrict__ cnt,
    const float* __restrict__ As, const float* __restrict__ Ad,
    const float* __restrict__ bias, float* __restrict__ G, int N) {
    const int lane = threadIdx.x & 63;
    const int node = (blockIdx.x * 256 + threadIdx.x) >> 6;
    if (node >= N) return;
    const int s = start[node];
    const int deg = cnt[node] + 1;
    const float ad0 = Ad[node * 4 + 0], ad1 = Ad[node * 4 + 1];
    const float ad2 = Ad[node * 4 + 2], ad3 = Ad[node * 4 + 3];

    // pass 1: per-head max
    float m0 = -INFINITY, m1 = -INFINITY, m2 = -INFINITY, m3 = -INFINITY;
    for (int j = s + lane; j < s + deg; j += 64) {
        int u = col[j];
        m0 = fmaxf(m0, lrelu(As[u * 4 + 0] + ad0));
        m1 = fmaxf(m1, lrelu(As[u * 4 + 1] + ad1));
        m2 = fmaxf(m2, lrelu(As[u * 4 + 2] + ad2));
        m3 = fmaxf(m3, lrelu(As[u * 4 + 3] + ad3));
    }
#pragma unroll
    for (int m = 32; m >= 1; m >>= 1) {
        m0 = fmaxf(m0, __shfl_xor(m0, m));
        m1 = fmaxf(m1, __shfl_xor(m1, m));
        m2 = fmaxf(m2, __shfl_xor(m2, m));
        m3 = fmaxf(m3, __shfl_xor(m3, m));
    }
    // pass 2: denom
    float d0 = 0.f, d1 = 0.f, d2 = 0.f, d3 = 0.f;
    for (int j = s + lane; j < s + deg; j += 64) {
        int u = col[j];
        d0 += __expf(lrelu(As[u * 4 + 0] + ad0) - m0);
        d1 += __expf(lrelu(As[u * 4 + 1] + ad1) - m1);
        d2 += __expf(lrelu(As[u * 4 + 2] + ad2) - m2);
        d3 += __expf(lrelu(As[u * 4 + 3] + ad3) - m3);
    }
#pragma unroll
    for (int m = 32; m >= 1; m >>= 1) {
        d0 += __shfl_xor(d0, m);
        d1 += __shfl_xor(d1, m);
        d2 += __shfl_xor(d2, m);
        d3 += __shfl_xor(d3, m);
    }
    const float iv0 = 1.f / (d0 + 1e-16f), iv1 = 1.f / (d1 + 1e-16f);
    const float iv2 = 1.f / (d2 + 1e-16f), iv3 = 1.f / (d3 + 1e-16f);

    // per-lane head selection: channel l -> head l>>5 (0/1); channel l+64 -> head 2+(l>>5)
    const bool lo = lane < 32;
    const float adA = lo ? ad0 : ad1, mA = lo ? m0 : m1, ivA = lo ? iv0 : iv1;
    const float adB = lo ? ad2 : ad3, mB = lo ? m2 : m3, ivB = lo ? iv2 : iv3;
    const int hsel = lane >> 5;

    float acc0 = 0.f, acc1 = 0.f;
    // pass 3: weighted feature accumulation (uniform edge loop, coalesced gathers)
    for (int j = s; j < s + deg; ++j) {
        int u = col[j];
        float aA = As[u * 4 + hsel];
        float aB = As[u * 4 + 2 + hsel];
        float w0 = __expf(lrelu(aA + adA) - mA) * ivA;
        float w1 = __expf(lrelu(aB + adB) - mB) * ivB;
        acc0 += w0 * Hm[u * 128 + lane];
        acc1 += w1 * Hm[u * 128 + 64 + lane];
    }
    float v0 = acc0 + bias[lane];
    float v1 = acc1 + bias[64 + lane];
    G[node * 128 + lane] = v0 > 0.f ? v0 : expm1f(v0);
    G[node * 128 + 64 + lane] = v1 > 0.f ? v1 : expm1f(v1);
}

// ---------------- Aggregation layer 2 (H=1, +bias) ----------------

__global__ __launch_bounds__(256) void agg2_kernel(
    const float* __restrict__ Hm, const int* __restrict__ col,
    const int* __restrict__ start, const int* __restrict__ cnt,
    const float* __restrict__ As, const float* __restrict__ Ad,
    const float* __restrict__ bias, float* __restrict__ Out, int N) {
    const int lane = threadIdx.x & 63;
    const int node = (blockIdx.x * 256 + threadIdx.x) >> 6;
    if (node >= N) return;
    const int s = start[node];
    const int deg = cnt[node] + 1;
    const float ad = Ad[node];

    float mx = -INFINITY;
    for (int j = s + lane; j < s + deg; j += 64) {
        int u = col[j];
        mx = fmaxf(mx, lrelu(As[u] + ad));
    }
#pragma unroll
    for (int m = 32; m >= 1; m >>= 1) mx = fmaxf(mx, __shfl_xor(mx, m));

    float dsum = 0.f;
    for (int j = s + lane; j < s + deg; j += 64) {
        int u = col[j];
        dsum += __expf(lrelu(As[u] + ad) - mx);
    }
#pragma unroll
    for (int m = 32; m >= 1; m >>= 1) dsum += __shfl_xor(dsum, m);
    const float iv = 1.f / (dsum + 1e-16f);

    float acc0 = 0.f, acc1 = 0.f;
    for (int j = s; j < s + deg; ++j) {
        int u = col[j];
        float w = __expf(lrelu(As[u] + ad) - mx) * iv;
        acc0 += w * Hm[u * 128 + lane];
        acc1 += w * Hm[u * 128 + 64 + lane];
    }
    Out[node * 128 + lane] = acc0 + bias[lane];
    Out[node * 128 + 64 + lane] = acc1 + bias[64 + lane];
}

// ---------------- launch ----------------

static inline size_t align256(size_t x) { return (x + 255) & ~(size_t)255; }

extern "C" void kernel_launch(void* const* d_in, const int* in_sizes, int n_in,
                              void* d_out, int out_size, void* d_ws, size_t ws_size,
                              hipStream_t stream) {
    const float* x = (const float*)d_in[0];
    const int* edge_index = (const int*)d_in[1];
    const float* W1 = (const float*)d_in[2];
    const float* a_src1 = (const float*)d_in[3];
    const float* a_dst1 = (const float*)d_in[4];
    const float* b1 = (const float*)d_in[5];
    const float* W2 = (const float*)d_in[6];
    const float* a_src2 = (const float*)d_in[7];
    const float* a_dst2 = (const float*)d_in[8];
    const float* b2 = (const float*)d_in[9];

    const int N = in_sizes[0] / 128;
    const int E = in_sizes[1] / 2;
    const int* src = edge_index;
    const int* dst = edge_index + E;

    // workspace layout (~63 MB total; second N*128 intermediate lives in d_out)
    char* ws = (char*)d_ws;
    size_t off = 0;
    int* cnt = (int*)(ws + off);   off += align256((size_t)N * 4);
    int* fill = (int*)(ws + off);  off += align256((size_t)N * 4);
    int* total = (int*)(ws + off); off += 256;
    size_t zero_bytes = off;       // cnt + fill + total must be zeroed
    int* start = (int*)(ws + off); off += align256((size_t)N * 4);
    int* col = (int*)(ws + off);   off += align256((size_t)(E + N) * 4);
    float* As1 = (float*)(ws + off); off += align256((size_t)N * 16);
    float* Ad1 = (float*)(ws + off); off += align256((size_t)N * 16);
    float* As2 = (float*)(ws + off); off += align256((size_t)N * 4);
    float* Ad2 = (float*)(ws + off); off += align256((size_t)N * 4);
    float* bufA = (float*)(ws + off); off += align256((size_t)N * 128 * 4); // h1, then h2
    float* bufB = (float*)d_out;   // g1 = elu(out1); safely overwritten by agg2 at the end
    (void)ws_size;

    hipMemsetAsync(d_ws, 0, zero_bytes, stream);

    // CSR build
    hist_kernel<<<2048, 256, 0, stream>>>(dst, E, cnt);
    alloc_kernel<<<(N + 255) / 256, 256, 0, stream>>>(cnt, N, start, total);
    scatter_kernel<<<2048, 256, 0, stream>>>(src, dst, E, N, start, fill, col);

    // layer 1
    gemm_alpha_kernel<4><<<512, 256, 0, stream>>>(x, W1, a_src1, a_dst1, bufA, As1, Ad1, N);
    agg1_kernel<<<(N + 3) / 4, 256, 0, stream>>>(bufA, col, start, cnt, As1, Ad1, b1, bufB, N);

    // layer 2 (h2 overwrites bufA; gemm2 reads g1 from d_out, agg2 then overwrites d_out)
    gemm_alpha_kernel<1><<<512, 256, 0, stream>>>(bufB, W2, a_src2, a_dst2, bufA, As2, Ad2, N);
    agg2_kernel<<<(N + 3) / 4, 256, 0, stream>>>(bufA, col, start, cnt, As2, Ad2, b2, (float*)d_out, N);
}

// Round 3
// 831.259 us; speedup vs baseline: 1.4467x; 1.4467x over previous
//
#include <hip/hip_runtime.h>
#include <math.h>

#define NEG_SLOPE 0.2f

__device__ __forceinline__ float lrelu(float x) { return x >= 0.f ? x : NEG_SLOPE * x; }

// ---------------- CSR build (by dst) ----------------

__global__ void hist_kernel(const int* __restrict__ dst, int E, int* __restrict__ cnt) {
    int i = blockIdx.x * blockDim.x + threadIdx.x;
    int stride = gridDim.x * blockDim.x;
    for (; i < E; i += stride) atomicAdd(&cnt[dst[i]], 1);
}

__global__ void alloc_kernel(const int* __restrict__ cnt, int N,
                             int* __restrict__ start, int* __restrict__ total) {
    int i = blockIdx.x * blockDim.x + threadIdx.x;
    int stride = gridDim.x * blockDim.x;
    for (; i < N; i += stride) start[i] = atomicAdd(total, cnt[i] + 1);  // +1 self loop
}

__global__ void scatter_kernel(const int* __restrict__ src, const int* __restrict__ dst,
                               int E, int N, const int* __restrict__ start,
                               int* __restrict__ fill, int* __restrict__ col) {
    int i = blockIdx.x * blockDim.x + threadIdx.x;
    int stride = gridDim.x * blockDim.x;
    int tot = E + N;
    for (; i < tot; i += stride) {
        int s, d;
        if (i < E) { s = src[i]; d = dst[i]; }
        else       { s = i - E; d = s; }       // self loop
        int p = start[d] + atomicAdd(&fill[d], 1);
        col[p] = s;
    }
}

// ---------------- Register-tiled GEMM (M x 128 @ 128 x 128) + alpha epilogue ----
// Block: 256 threads -> 64 rows x 128 cols tile. Thread (tx=tid&31, ty=tid>>5)
// owns rows ty*8..ty*8+7, cols tx*4..tx*4+3 (8x4 = 32 accumulators).
// K sliced in blocks of 32: Xs transposed [k][row] 8KB, Ws [k][col] 16KB -> 24KB LDS.

template <int H>
__global__ __launch_bounds__(256) void gemm_tiled_kernel(
    const float* __restrict__ X, const float* __restrict__ W,
    const float* __restrict__ avs, const float* __restrict__ avd,
    float* __restrict__ Hm, float* __restrict__ As, float* __restrict__ Ad, int N) {
    __shared__ float Xs[32][64];    // [k][row]
    __shared__ float Ws[32][128];   // [k][col]
    const int tid = threadIdx.x;
    const int tx = tid & 31;
    const int ty = tid >> 5;
    const int row0 = blockIdx.x * 64;

    float acc[8][4];
#pragma unroll
    for (int r = 0; r < 8; ++r)
#pragma unroll
        for (int c = 0; c < 4; ++c) acc[r][c] = 0.f;

    const float4 as_v = *(const float4*)(avs + tx * 4);
    const float4 ad_v = *(const float4*)(avd + tx * 4);

    for (int k0 = 0; k0 < 128; k0 += 32) {
        // stage Xs (transpose): 64 rows x 8 float4-chunks = 512 chunks, 2/thread
#pragma unroll
        for (int i = 0; i < 2; ++i) {
            int c = tid + 256 * i;
            int r = c & 63;
            int kc = (c >> 6) << 2;            // 0,4,...,28
            int grow = row0 + r;
            float4 v = make_float4(0.f, 0.f, 0.f, 0.f);
            if (grow < N) v = *(const float4*)(X + (size_t)grow * 128 + k0 + kc);
            Xs[kc + 0][r] = v.x;
            Xs[kc + 1][r] = v.y;
            Xs[kc + 2][r] = v.z;
            Xs[kc + 3][r] = v.w;
        }
        // stage Ws: 32 x 128 = 1024 float4-chunks, 4/thread (no transpose)
#pragma unroll
        for (int i = 0; i < 4; ++i) {
            int c = tid + 256 * i;
            int kk = c >> 5;
            int cc = (c & 31) << 2;
            *(float4*)(&Ws[kk][cc]) = *(const float4*)(W + (size_t)(k0 + kk) * 128 + cc);
        }
        __syncthreads();
#pragma unroll
        for (int k = 0; k < 32; ++k) {
            float4 xa = *(const float4*)(&Xs[k][ty * 8]);
            float4 xb = *(const float4*)(&Xs[k][ty * 8 + 4]);
            float4 wv = *(const float4*)(&Ws[k][tx * 4]);
            float xf[8] = {xa.x, xa.y, xa.z, xa.w, xb.x, xb.y, xb.z, xb.w};
            float wf[4] = {wv.x, wv.y, wv.z, wv.w};
#pragma unroll
            for (int r = 0; r < 8; ++r)
#pragma unroll
                for (int c = 0; c < 4; ++c) acc[r][c] += xf[r] * wf[c];
        }
        __syncthreads();
    }

    // store + fused alpha epilogue
#pragma unroll
    for (int r = 0; r < 8; ++r) {
        int grow = row0 + ty * 8 + r;
        if (grow >= N) continue;   // uniform across each 32-lane half
        float4 o = make_float4(acc[r][0], acc[r][1], acc[r][2], acc[r][3]);
        *(float4*)(Hm + (size_t)grow * 128 + tx * 4) = o;
        float ps = o.x * as_v.x + o.y * as_v.y + o.z * as_v.z + o.w * as_v.w;
        float pd = o.x * ad_v.x + o.y * ad_v.y + o.z * ad_v.z + o.w * ad_v.w;
        if (H == 4) {
            // head = tx>>3; reduce across the 8 lanes of that head's col block
            ps += __shfl_xor(ps, 1); ps += __shfl_xor(ps, 2); ps += __shfl_xor(ps, 4);
            pd += __shfl_xor(pd, 1); pd += __shfl_xor(pd, 2); pd += __shfl_xor(pd, 4);
            if ((tx & 7) == 0) {
                int h = tx >> 3;
                As[(size_t)grow * 4 + h] = ps;
                Ad[(size_t)grow * 4 + h] = pd;
            }
        } else {
            // single head: reduce across all 32 col lanes
#pragma unroll
            for (int m = 1; m <= 16; m <<= 1) {
                ps += __shfl_xor(ps, m);
                pd += __shfl_xor(pd, m);
            }
            if (tx == 0) { As[grow] = ps; Ad[grow] = pd; }
        }
    }
}

// ---------------- Aggregation layer 1 (H=4, +bias, ELU) ----------------
// One wave per dst node. lane l owns channels l and l+64.

__global__ __launch_bounds__(256) void agg1_kernel(
    const float* __restrict__ Hm, const int* __restrict__ col,
    const int* __restrict__ start, const int* __restrict__ cnt,
    const float* __restrict__ As, const float* __restrict__ Ad,
    const float* __restrict__ bias, float* __restrict__ G, int N) {
    const int lane = threadIdx.x & 63;
    const int node = (blockIdx.x * 256 + threadIdx.x) >> 6;
    if (node >= N) return;
    const int s = start[node];
    const int deg = cnt[node] + 1;
    const float ad0 = Ad[node * 4 + 0], ad1 = Ad[node * 4 + 1];
    const float ad2 = Ad[node * 4 + 2], ad3 = Ad[node * 4 + 3];

    // pass 1: per-head max
    float m0 = -INFINITY, m1 = -INFINITY, m2 = -INFINITY, m3 = -INFINITY;
    for (int j = s + lane; j < s + deg; j += 64) {
        int u = col[j];
        m0 = fmaxf(m0, lrelu(As[u * 4 + 0] + ad0));
        m1 = fmaxf(m1, lrelu(As[u * 4 + 1] + ad1));
        m2 = fmaxf(m2, lrelu(As[u * 4 + 2] + ad2));
        m3 = fmaxf(m3, lrelu(As[u * 4 + 3] + ad3));
    }
#pragma unroll
    for (int m = 32; m >= 1; m >>= 1) {
        m0 = fmaxf(m0, __shfl_xor(m0, m));
        m1 = fmaxf(m1, __shfl_xor(m1, m));
        m2 = fmaxf(m2, __shfl_xor(m2, m));
        m3 = fmaxf(m3, __shfl_xor(m3, m));
    }
    // pass 2: denom
    float d0 = 0.f, d1 = 0.f, d2 = 0.f, d3 = 0.f;
    for (int j = s + lane; j < s + deg; j += 64) {
        int u = col[j];
        d0 += __expf(lrelu(As[u * 4 + 0] + ad0) - m0);
        d1 += __expf(lrelu(As[u * 4 + 1] + ad1) - m1);
        d2 += __expf(lrelu(As[u * 4 + 2] + ad2) - m2);
        d3 += __expf(lrelu(As[u * 4 + 3] + ad3) - m3);
    }
#pragma unroll
    for (int m = 32; m >= 1; m >>= 1) {
        d0 += __shfl_xor(d0, m);
        d1 += __shfl_xor(d1, m);
        d2 += __shfl_xor(d2, m);
        d3 += __shfl_xor(d3, m);
    }
    const float iv0 = 1.f / (d0 + 1e-16f), iv1 = 1.f / (d1 + 1e-16f);
    const float iv2 = 1.f / (d2 + 1e-16f), iv3 = 1.f / (d3 + 1e-16f);

    // per-lane head selection: channel l -> head l>>5 (0/1); channel l+64 -> head 2+(l>>5)
    const bool lo = lane < 32;
    const float adA = lo ? ad0 : ad1, mA = lo ? m0 : m1, ivA = lo ? iv0 : iv1;
    const float adB = lo ? ad2 : ad3, mB = lo ? m2 : m3, ivB = lo ? iv2 : iv3;
    const int hsel = lane >> 5;

    float acc0 = 0.f, acc1 = 0.f;
    // pass 3: weighted feature accumulation (uniform edge loop, coalesced gathers)
    for (int j = s; j < s + deg; ++j) {
        int u = col[j];
        float aA = As[u * 4 + hsel];
        float aB = As[u * 4 + 2 + hsel];
        float w0 = __expf(lrelu(aA + adA) - mA) * ivA;
        float w1 = __expf(lrelu(aB + adB) - mB) * ivB;
        acc0 += w0 * Hm[u * 128 + lane];
        acc1 += w1 * Hm[u * 128 + 64 + lane];
    }
    float v0 = acc0 + bias[lane];
    float v1 = acc1 + bias[64 + lane];
    G[node * 128 + lane] = v0 > 0.f ? v0 : expm1f(v0);
    G[node * 128 + 64 + lane] = v1 > 0.f ? v1 : expm1f(v1);
}

// ---------------- Aggregation layer 2 (H=1, +bias) ----------------

__global__ __launch_bounds__(256) void agg2_kernel(
    const float* __restrict__ Hm, const int* __restrict__ col,
    const int* __restrict__ start, const int* __restrict__ cnt,
    const float* __restrict__ As, const float* __restrict__ Ad,
    const float* __restrict__ bias, float* __restrict__ Out, int N) {
    const int lane = threadIdx.x & 63;
    const int node = (blockIdx.x * 256 + threadIdx.x) >> 6;
    if (node >= N) return;
    const int s = start[node];
    const int deg = cnt[node] + 1;
    const float ad = Ad[node];

    float mx = -INFINITY;
    for (int j = s + lane; j < s + deg; j += 64) {
        int u = col[j];
        mx = fmaxf(mx, lrelu(As[u] + ad));
    }
#pragma unroll
    for (int m = 32; m >= 1; m >>= 1) mx = fmaxf(mx, __shfl_xor(mx, m));

    float dsum = 0.f;
    for (int j = s + lane; j < s + deg; j += 64) {
        int u = col[j];
        dsum += __expf(lrelu(As[u] + ad) - mx);
    }
#pragma unroll
    for (int m = 32; m >= 1; m >>= 1) dsum += __shfl_xor(dsum, m);
    const float iv = 1.f / (dsum + 1e-16f);

    float acc0 = 0.f, acc1 = 0.f;
    for (int j = s; j < s + deg; ++j) {
        int u = col[j];
        float w = __expf(lrelu(As[u] + ad) - mx) * iv;
        acc0 += w * Hm[u * 128 + lane];
        acc1 += w * Hm[u * 128 + 64 + lane];
    }
    Out[node * 128 + lane] = acc0 + bias[lane];
    Out[node * 128 + 64 + lane] = acc1 + bias[64 + lane];
}

// ---------------- launch ----------------

static inline size_t align256(size_t x) { return (x + 255) & ~(size_t)255; }

extern "C" void kernel_launch(void* const* d_in, const int* in_sizes, int n_in,
                              void* d_out, int out_size, void* d_ws, size_t ws_size,
                              hipStream_t stream) {
    const float* x = (const float*)d_in[0];
    const int* edge_index = (const int*)d_in[1];
    const float* W1 = (const float*)d_in[2];
    const float* a_src1 = (const float*)d_in[3];
    const float* a_dst1 = (const float*)d_in[4];
    const float* b1 = (const float*)d_in[5];
    const float* W2 = (const float*)d_in[6];
    const float* a_src2 = (const float*)d_in[7];
    const float* a_dst2 = (const float*)d_in[8];
    const float* b2 = (const float*)d_in[9];

    const int N = in_sizes[0] / 128;
    const int E = in_sizes[1] / 2;
    const int* src = edge_index;
    const int* dst = edge_index + E;

    // workspace layout (~63 MB total; second N*128 intermediate lives in d_out)
    char* ws = (char*)d_ws;
    size_t off = 0;
    int* cnt = (int*)(ws + off);   off += align256((size_t)N * 4);
    int* fill = (int*)(ws + off);  off += align256((size_t)N * 4);
    int* total = (int*)(ws + off); off += 256;
    size_t zero_bytes = off;       // cnt + fill + total must be zeroed
    int* start = (int*)(ws + off); off += align256((size_t)N * 4);
    int* col = (int*)(ws + off);   off += align256((size_t)(E + N) * 4);
    float* As1 = (float*)(ws + off); off += align256((size_t)N * 16);
    float* Ad1 = (float*)(ws + off); off += align256((size_t)N * 16);
    float* As2 = (float*)(ws + off); off += align256((size_t)N * 4);
    float* Ad2 = (float*)(ws + off); off += align256((size_t)N * 4);
    float* bufA = (float*)(ws + off); off += align256((size_t)N * 128 * 4); // h1, then h2
    float* bufB = (float*)d_out;   // g1 = elu(out1); safely overwritten by agg2 at the end
    (void)ws_size;

    hipMemsetAsync(d_ws, 0, zero_bytes, stream);

    // CSR build
    hist_kernel<<<2048, 256, 0, stream>>>(dst, E, cnt);
    alloc_kernel<<<(N + 255) / 256, 256, 0, stream>>>(cnt, N, start, total);
    scatter_kernel<<<2048, 256, 0, stream>>>(src, dst, E, N, start, fill, col);

    const int gtiles = (N + 63) / 64;

    // layer 1
    gemm_tiled_kernel<4><<<gtiles, 256, 0, stream>>>(x, W1, a_src1, a_dst1, bufA, As1, Ad1, N);
    agg1_kernel<<<(N + 3) / 4, 256, 0, stream>>>(bufA, col, start, cnt, As1, Ad1, b1, bufB, N);

    // layer 2 (h2 overwrites bufA; gemm2 reads g1 from d_out, agg2 then overwrites d_out)
    gemm_tiled_kernel<1><<<gtiles, 256, 0, stream>>>(bufB, W2, a_src2, a_dst2, bufA, As2, Ad2, N);
    agg2_kernel<<<(N + 3) / 4, 256, 0, stream>>>(bufA, col, start, cnt, As2, Ad2, b2, (float*)d_out, N);
}